// Round 2
// baseline (497.652 us; speedup 1.0000x reference)
//
#include <hip/hip_runtime.h>
#include <math.h>

// Problem constants: N=32768 nodes, E=262144 edges, HID=64, HEADS=4
#define HIDDEN 64
#define HEADS 4
#define HC 256   // HEADS * HIDDEN

// ---------------- CSR build ----------------

__global__ void k_zero(int* p, int n) {
    int i = blockIdx.x * blockDim.x + threadIdx.x;
    if (i < n) p[i] = 0;
}

__global__ void k_count(const int* __restrict__ dst, int* __restrict__ counts, int E) {
    int e = blockIdx.x * blockDim.x + threadIdx.x;
    if (e < E) atomicAdd(&counts[dst[e]], 1);
}

// 1 block, 1024 threads, each handles 32 entries. N must be 32768.
__global__ void k_scan(const int* __restrict__ counts, int* __restrict__ offs, int N) {
    __shared__ int sdata[1024];
    int t = threadIdx.x;
    int base = t * 32;
    int run = 0;
    for (int i = 0; i < 32; ++i) run += counts[base + i];
    sdata[t] = run;
    __syncthreads();
    for (int d = 1; d < 1024; d <<= 1) {
        int v = (t >= d) ? sdata[t - d] : 0;
        __syncthreads();
        sdata[t] += v;
        __syncthreads();
    }
    int chunk = (t == 0) ? 0 : sdata[t - 1];
    int running = chunk;
    for (int i = 0; i < 32; ++i) {
        offs[base + i] = running;
        running += counts[base + i];
    }
    if (t == 1023) offs[N] = running;
}

__global__ void k_copy(const int* __restrict__ a, int* __restrict__ b, int n) {
    int i = blockIdx.x * blockDim.x + threadIdx.x;
    if (i < n) b[i] = a[i];
}

__global__ void k_fill(const int* __restrict__ dst, int* __restrict__ cursor,
                       int* __restrict__ elist, int E) {
    int e = blockIdx.x * blockDim.x + threadIdx.x;
    if (e < E) {
        int p = atomicAdd(&cursor[dst[e]], 1);
        elist[p] = e;
    }
}

// ---------------- per-layer kernels ----------------

// We_red[d][h] = sum_c We[d, h*64+c] * att_edge[h, c].  768 threads = 12 waves.
__global__ void k_wered(const float* __restrict__ We, const float* __restrict__ atte,
                        float* __restrict__ wr) {
    int t = threadIdx.x;
    int w = t >> 6, lane = t & 63;
    int d = w >> 2, h = w & 3;
    float v = We[d * HC + h * HIDDEN + lane] * atte[h * HIDDEN + lane];
    for (int o = 32; o > 0; o >>= 1) v += __shfl_down(v, o);
    if (lane == 0) wr[d * HEADS + h] = v;
}

// alpha_e[e,h] = sum_d edge_attr[e,d] * wr[d,h]
__global__ __launch_bounds__(256) void k_alphae(const float* __restrict__ ea,
                                                const float* __restrict__ wr,
                                                float* __restrict__ ae, int E) {
    int e = blockIdx.x * blockDim.x + threadIdx.x;
    if (e >= E) return;
    float a0 = ea[e * 3 + 0];
    float a1 = ea[e * 3 + 1];
    float a2 = ea[e * 3 + 2];
#pragma unroll
    for (int h = 0; h < 4; ++h)
        ae[e * 4 + h] = a0 * wr[h] + a1 * wr[4 + h] + a2 * wr[8 + h];
}

// x[n,:] = z[n,:] @ W  (64 -> 256), plus fused alpha_src/alpha_dst per head.
// One block per node, 256 threads (thread t -> output column t; wave = head).
__global__ __launch_bounds__(256) void k_transform(const float* __restrict__ z,
                                                   const float* __restrict__ W,
                                                   const float* __restrict__ asw,
                                                   const float* __restrict__ adw,
                                                   float* __restrict__ x,
                                                   float* __restrict__ as_,
                                                   float* __restrict__ ad_) {
    __shared__ float zrow[HIDDEN];
    int n = blockIdx.x, t = threadIdx.x;
    if (t < HIDDEN) zrow[t] = z[n * HIDDEN + t];
    __syncthreads();
    float acc = 0.f;
#pragma unroll
    for (int d = 0; d < HIDDEN; ++d) acc += zrow[d] * W[d * HC + t];
    x[n * HC + t] = acc;
    int h = t >> 6, lane = t & 63;
    float vs = acc * asw[t];
    float vd = acc * adw[t];
    for (int o = 32; o > 0; o >>= 1) {
        vs += __shfl_down(vs, o);
        vd += __shfl_down(vd, o);
    }
    if (lane == 0) {
        as_[n * HEADS + h] = vs;
        ad_[n * HEADS + h] = vd;
    }
}

// Per-node: segment softmax over in-edges + weighted aggregation + head mean
// + bias + LayerNorm + SiLU. One block per node; wave h handles head h;
// lane = channel in pass 2 / epilogue.
__global__ __launch_bounds__(256) void k_aggregate(
        const float* __restrict__ x, const float* __restrict__ as_,
        const float* __restrict__ ad_, const float* __restrict__ ae,
        const int* __restrict__ src, const int* __restrict__ offs,
        const int* __restrict__ elist,
        const float* __restrict__ bias, const float* __restrict__ lng,
        const float* __restrict__ lnb,
        float* __restrict__ out) {
    __shared__ float sh[HEADS][HIDDEN];
    int n = blockIdx.x, t = threadIdx.x;
    int h = t >> 6, lane = t & 63;
    int beg = offs[n], end = offs[n + 1];
    int deg = end - beg;
    float ad = ad_[n * HEADS + h];

    // pass 1: online softmax (max m, sum ssum) over this node's in-edges
    float m = -INFINITY, ssum = 0.f;
    for (int i = lane; i < deg; i += 64) {
        int eid = elist[beg + i];
        int s = src[eid];
        float lg = as_[s * HEADS + h] + ad + ae[eid * 4 + h];
        lg = (lg >= 0.f) ? lg : 0.2f * lg;
        if (lg > m) {
            ssum = ssum * __expf(m - lg) + 1.f;  // expf(-inf)=0 handles first iter
            m = lg;
        } else {
            ssum += __expf(lg - m);
        }
    }
    // wave tree-reduce of (m, ssum); result valid at lane 0
    for (int o = 32; o > 0; o >>= 1) {
        float m2 = __shfl_down(m, o);
        float s2 = __shfl_down(ssum, o);
        float mn = fmaxf(m, m2);
        float t1 = (m == -INFINITY) ? 0.f : ssum * __expf(m - mn);
        float t2 = (m2 == -INFINITY) ? 0.f : s2 * __expf(m2 - mn);
        m = mn;
        ssum = t1 + t2;
    }
    m = __shfl(m, 0);
    ssum = __shfl(ssum, 0);
    float winv = 1.f / (ssum + 1e-16f);

    // pass 2: edge-sequential weighted gather; lane = channel
    float acc = 0.f;
    for (int i = 0; i < deg; ++i) {
        int eid = elist[beg + i];
        int s = src[eid];
        float lg = as_[s * HEADS + h] + ad + ae[eid * 4 + h];
        lg = (lg >= 0.f) ? lg : 0.2f * lg;
        float wgt = __expf(lg - m) * winv;
        acc += wgt * x[s * HC + h * HIDDEN + lane];
    }
    sh[h][lane] = acc;
    __syncthreads();

    // epilogue on wave 0: head mean + bias + LayerNorm + SiLU
    if (t < HIDDEN) {
        int c = t;
        float u = (sh[0][c] + sh[1][c] + sh[2][c] + sh[3][c]) * 0.25f + bias[c];
        float mu = u;
        for (int o = 32; o > 0; o >>= 1) mu += __shfl_xor(mu, o);
        mu *= (1.f / 64.f);
        float dlt = u - mu;
        float var = dlt * dlt;
        for (int o = 32; o > 0; o >>= 1) var += __shfl_xor(var, o);
        var *= (1.f / 64.f);
        float y = dlt * rsqrtf(var + 1e-5f) * lng[c] + lnb[c];
        float r = y / (1.f + __expf(-y));  // silu
        out[n * HIDDEN + c] = r;
    }
}

// ---------------- launch ----------------

extern "C" void kernel_launch(void* const* d_in, const int* in_sizes, int n_in,
                              void* d_out, int out_size, void* d_ws, size_t ws_size,
                              hipStream_t stream) {
    const float* h   = (const float*)d_in[1];
    const int*   ei  = (const int*)d_in[2];
    const float* ea  = (const float*)d_in[3];
    const float* W1  = (const float*)d_in[4];
    const float* We1 = (const float*)d_in[5];
    const float* as1 = (const float*)d_in[6];
    const float* ad1 = (const float*)d_in[7];
    const float* ae1 = (const float*)d_in[8];
    const float* b1  = (const float*)d_in[9];
    const float* lg1 = (const float*)d_in[10];
    const float* lb1 = (const float*)d_in[11];
    const float* W2  = (const float*)d_in[12];
    const float* We2 = (const float*)d_in[13];
    const float* as2 = (const float*)d_in[14];
    const float* ad2 = (const float*)d_in[15];
    const float* ae2 = (const float*)d_in[16];
    const float* b2  = (const float*)d_in[17];
    const float* lg2 = (const float*)d_in[18];
    const float* lb2 = (const float*)d_in[19];

    const int N = in_sizes[1] / HIDDEN;   // 32768
    const int E = in_sizes[2] / 2;        // 262144
    const int* srcp = ei;
    const int* dstp = ei + E;

    // workspace layout (all regions fully written before read)
    char* w = (char*)d_ws;
    float* x      = (float*)w;  w += (size_t)N * HC * 4;        // 33.5 MB
    float* as_    = (float*)w;  w += (size_t)N * HEADS * 4;
    float* adv    = (float*)w;  w += (size_t)N * HEADS * 4;
    float* ae     = (float*)w;  w += (size_t)E * 4 * 4;         // 4 MB
    float* z1     = (float*)w;  w += (size_t)N * HIDDEN * 4;    // 8 MB
    float* wr     = (float*)w;  w += 256;
    int* counts   = (int*)w;    w += (size_t)N * 4;             // doubles as cursor
    int* offs     = (int*)w;    w += (size_t)(N + 1) * 4 + 252;
    int* elist    = (int*)w;    w += (size_t)E * 4;

    // CSR by dst (shared across both layers)
    k_zero<<<(N + 255) / 256, 256, 0, stream>>>(counts, N);
    k_count<<<(E + 255) / 256, 256, 0, stream>>>(dstp, counts, E);
    k_scan<<<1, 1024, 0, stream>>>(counts, offs, N);
    k_copy<<<(N + 255) / 256, 256, 0, stream>>>(offs, counts, N);
    k_fill<<<(E + 255) / 256, 256, 0, stream>>>(dstp, counts, elist, E);

    // layer 1
    k_transform<<<N, 256, 0, stream>>>(h, W1, as1, ad1, x, as_, adv);
    k_wered<<<1, 768, 0, stream>>>(We1, ae1, wr);
    k_alphae<<<(E + 255) / 256, 256, 0, stream>>>(ea, wr, ae, E);
    k_aggregate<<<N, 256, 0, stream>>>(x, as_, adv, ae, srcp, offs, elist,
                                       b1, lg1, lb1, z1);
    // layer 2
    k_transform<<<N, 256, 0, stream>>>(z1, W2, as2, ad2, x, as_, adv);
    k_wered<<<1, 768, 0, stream>>>(We2, ae2, wr);
    k_alphae<<<(E + 255) / 256, 256, 0, stream>>>(ea, wr, ae, E);
    k_aggregate<<<N, 256, 0, stream>>>(x, as_, adv, ae, srcp, offs, elist,
                                       b2, lg2, lb2, (float*)d_out);
}

// Round 3
// 429.530 us; speedup vs baseline: 1.1586x; 1.1586x over previous
//
#include <hip/hip_runtime.h>
#include <math.h>

// Problem constants: N=32768 nodes, E=262144 edges, HID=64, HEADS=4
#define HIDDEN 64
#define HEADS 4
#define HC 256   // HEADS * HIDDEN

// ---------------- CSR build ----------------

__global__ void k_zero(int* p, int n) {
    int i = blockIdx.x * blockDim.x + threadIdx.x;
    if (i < n) p[i] = 0;
}

__global__ void k_count(const int* __restrict__ dst, int* __restrict__ counts, int E) {
    int e = blockIdx.x * blockDim.x + threadIdx.x;
    if (e < E) atomicAdd(&counts[dst[e]], 1);
}

// 1 block, 1024 threads, each handles 32 entries. N must be 32768.
__global__ void k_scan(const int* __restrict__ counts, int* __restrict__ offs, int N) {
    __shared__ int sdata[1024];
    int t = threadIdx.x;
    int base = t * 32;
    int run = 0;
    for (int i = 0; i < 32; ++i) run += counts[base + i];
    sdata[t] = run;
    __syncthreads();
    for (int d = 1; d < 1024; d <<= 1) {
        int v = (t >= d) ? sdata[t - d] : 0;
        __syncthreads();
        sdata[t] += v;
        __syncthreads();
    }
    int chunk = (t == 0) ? 0 : sdata[t - 1];
    int running = chunk;
    for (int i = 0; i < 32; ++i) {
        offs[base + i] = running;
        running += counts[base + i];
    }
    if (t == 1023) offs[N] = running;
}

__global__ void k_copy(const int* __restrict__ a, int* __restrict__ b, int n) {
    int i = blockIdx.x * blockDim.x + threadIdx.x;
    if (i < n) b[i] = a[i];
}

// fill: also emit src in dst-sorted order so aggregate reads it contiguously
__global__ void k_fill(const int* __restrict__ dst, const int* __restrict__ src,
                       int* __restrict__ cursor, int* __restrict__ elist,
                       int* __restrict__ ssorted, int E) {
    int e = blockIdx.x * blockDim.x + threadIdx.x;
    if (e < E) {
        int p = atomicAdd(&cursor[dst[e]], 1);
        elist[p] = e;
        ssorted[p] = src[e];
    }
}

// ---------------- per-layer kernels ----------------

// We_red[d][h] = sum_c We[d, h*64+c] * att_edge[h, c].  768 threads = 12 waves.
__global__ void k_wered(const float* __restrict__ We, const float* __restrict__ atte,
                        float* __restrict__ wr) {
    int t = threadIdx.x;
    int w = t >> 6, lane = t & 63;
    int d = w >> 2, h = w & 3;
    float v = We[d * HC + h * HIDDEN + lane] * atte[h * HIDDEN + lane];
    for (int o = 32; o > 0; o >>= 1) v += __shfl_down(v, o);
    if (lane == 0) wr[d * HEADS + h] = v;
}

// LDS-tiled transform: x = z @ W (64 -> 256) + fused per-head alpha_src/alpha_dst.
// blockIdx.x = head (64-col tile), blockIdx.y = 128-node chunk. 256 thr = 4 waves.
__global__ __launch_bounds__(256) void k_transform(const float* __restrict__ z,
                                                   const float* __restrict__ W,
                                                   const float* __restrict__ asw,
                                                   const float* __restrict__ adw,
                                                   float* __restrict__ x,
                                                   float* __restrict__ as_,
                                                   float* __restrict__ ad_) {
    __shared__ float wlds[64 * 64];    // 16 KB: W[d][h*64+c]
    __shared__ float zlds[128 * 64];   // 32 KB: z rows of this chunk
    int h = blockIdx.x;
    int chunk = blockIdx.y;
    int t = threadIdx.x;

    float4* wl4 = (float4*)wlds;
#pragma unroll
    for (int r = 0; r < 4; ++r) {
        int idx = t + 256 * r;             // 1024 float4 = 64x64 floats
        int d = idx >> 4, c4 = idx & 15;
        wl4[idx] = *(const float4*)&W[d * HC + h * HIDDEN + c4 * 4];
    }
    float4* zl4 = (float4*)zlds;
    const float4* zg4 = (const float4*)(z + (size_t)chunk * 128 * HIDDEN);
#pragma unroll
    for (int r = 0; r < 8; ++r) zl4[t + 256 * r] = zg4[t + 256 * r];
    __syncthreads();

    int w = t >> 6, lane = t & 63;
    float wcol[64];
#pragma unroll
    for (int d = 0; d < 64; ++d) wcol[d] = wlds[d * 64 + lane];
    float aw = asw[h * HIDDEN + lane], dw = adw[h * HIDDEN + lane];

    for (int nn = w; nn < 128; nn += 4) {
        float acc = 0.f;
#pragma unroll
        for (int d = 0; d < 64; ++d) acc += zlds[nn * 64 + d] * wcol[d];
        int n = chunk * 128 + nn;
        x[(size_t)n * HC + h * HIDDEN + lane] = acc;
        float vs = acc * aw, vd = acc * dw;
#pragma unroll
        for (int o = 32; o > 0; o >>= 1) {
            vs += __shfl_down(vs, o);
            vd += __shfl_down(vd, o);
        }
        if (lane == 0) {
            as_[n * HEADS + h] = vs;
            ad_[n * HEADS + h] = vd;
        }
    }
}

// Per-edge logits in dst-sorted order: lsort[p][h] = leakyrelu(as[src]+ad[dst]+ae)
__global__ __launch_bounds__(256) void k_logits(
        const float* __restrict__ ea, const float* __restrict__ wr,
        const float* __restrict__ as_, const float* __restrict__ ad_,
        const int* __restrict__ elist, const int* __restrict__ ssorted,
        const int* __restrict__ dst, float* __restrict__ lsort, int E) {
    int p = blockIdx.x * blockDim.x + threadIdx.x;
    if (p >= E) return;
    int e = elist[p], s = ssorted[p], d = dst[e];
    float a0 = ea[e * 3 + 0];
    float a1 = ea[e * 3 + 1];
    float a2 = ea[e * 3 + 2];
#pragma unroll
    for (int h = 0; h < 4; ++h) {
        float lg = as_[s * 4 + h] + ad_[d * 4 + h]
                 + a0 * wr[h] + a1 * wr[4 + h] + a2 * wr[8 + h];
        lsort[p * 4 + h] = (lg >= 0.f) ? lg : 0.2f * lg;
    }
}

// Per-node: segment softmax (from precomputed sorted logits) + weighted gather
// + head mean + bias + LayerNorm + SiLU. wave = head, lane = channel in pass 2.
__global__ __launch_bounds__(256) void k_aggregate(
        const float* __restrict__ x, const float* __restrict__ lsort,
        const int* __restrict__ ssorted, const int* __restrict__ offs,
        const float* __restrict__ bias, const float* __restrict__ lng,
        const float* __restrict__ lnb, float* __restrict__ out) {
    __shared__ float sh[HEADS][HIDDEN];
    int n = blockIdx.x, t = threadIdx.x;
    int h = t >> 6, lane = t & 63;
    int beg = offs[n], deg = offs[n + 1] - beg;

    // max
    float m = -INFINITY;
    for (int i = lane; i < deg; i += 64) m = fmaxf(m, lsort[(beg + i) * 4 + h]);
#pragma unroll
    for (int o = 32; o > 0; o >>= 1) m = fmaxf(m, __shfl_xor(m, o));
    // sum
    float ssum = 0.f;
    for (int i = lane; i < deg; i += 64) ssum += __expf(lsort[(beg + i) * 4 + h] - m);
#pragma unroll
    for (int o = 32; o > 0; o >>= 1) ssum += __shfl_xor(ssum, o);
    float winv = 1.f / (ssum + 1e-16f);

    // edge-sequential weighted gather; lane = channel
    float acc = 0.f;
    for (int i = 0; i < deg; ++i) {
        float lg = lsort[(beg + i) * 4 + h];
        int s = ssorted[beg + i];
        float wgt = __expf(lg - m) * winv;
        acc += wgt * x[(size_t)s * HC + h * HIDDEN + lane];
    }
    sh[h][lane] = acc;
    __syncthreads();

    // epilogue on wave 0: head mean + bias + LayerNorm + SiLU
    if (t < HIDDEN) {
        int c = t;
        float u = (sh[0][c] + sh[1][c] + sh[2][c] + sh[3][c]) * 0.25f + bias[c];
        float mu = u;
#pragma unroll
        for (int o = 32; o > 0; o >>= 1) mu += __shfl_xor(mu, o);
        mu *= (1.f / 64.f);
        float dlt = u - mu;
        float var = dlt * dlt;
#pragma unroll
        for (int o = 32; o > 0; o >>= 1) var += __shfl_xor(var, o);
        var *= (1.f / 64.f);
        float y = dlt * rsqrtf(var + 1e-5f) * lng[c] + lnb[c];
        float r = y / (1.f + __expf(-y));  // silu
        out[n * HIDDEN + c] = r;
    }
}

// ---------------- launch ----------------

extern "C" void kernel_launch(void* const* d_in, const int* in_sizes, int n_in,
                              void* d_out, int out_size, void* d_ws, size_t ws_size,
                              hipStream_t stream) {
    const float* h   = (const float*)d_in[1];
    const int*   ei  = (const int*)d_in[2];
    const float* ea  = (const float*)d_in[3];
    const float* W1  = (const float*)d_in[4];
    const float* We1 = (const float*)d_in[5];
    const float* as1 = (const float*)d_in[6];
    const float* ad1 = (const float*)d_in[7];
    const float* ae1 = (const float*)d_in[8];
    const float* b1  = (const float*)d_in[9];
    const float* lg1 = (const float*)d_in[10];
    const float* lb1 = (const float*)d_in[11];
    const float* W2  = (const float*)d_in[12];
    const float* We2 = (const float*)d_in[13];
    const float* as2 = (const float*)d_in[14];
    const float* ad2 = (const float*)d_in[15];
    const float* ae2 = (const float*)d_in[16];
    const float* b2  = (const float*)d_in[17];
    const float* lg2 = (const float*)d_in[18];
    const float* lb2 = (const float*)d_in[19];

    const int N = in_sizes[1] / HIDDEN;   // 32768
    const int E = in_sizes[2] / 2;        // 262144
    const int* srcp = ei;
    const int* dstp = ei + E;

    // workspace layout (all regions fully written before read)
    char* w = (char*)d_ws;
    float* x      = (float*)w;  w += (size_t)N * HC * 4;        // 33.5 MB
    float* as_    = (float*)w;  w += (size_t)N * HEADS * 4;
    float* adv    = (float*)w;  w += (size_t)N * HEADS * 4;
    float* lsort  = (float*)w;  w += (size_t)E * 4 * 4;         // 4 MB
    float* z1     = (float*)w;  w += (size_t)N * HIDDEN * 4;    // 8 MB
    float* wr     = (float*)w;  w += 256;
    int* counts   = (int*)w;    w += (size_t)N * 4;             // doubles as cursor
    int* offs     = (int*)w;    w += (size_t)(N + 1) * 4 + 124; // pad to 16B
    int* elist    = (int*)w;    w += (size_t)E * 4;
    int* ssorted  = (int*)w;    w += (size_t)E * 4;

    // CSR by dst (shared across both layers)
    k_zero<<<(N + 255) / 256, 256, 0, stream>>>(counts, N);
    k_count<<<(E + 255) / 256, 256, 0, stream>>>(dstp, counts, E);
    k_scan<<<1, 1024, 0, stream>>>(counts, offs, N);
    k_copy<<<(N + 255) / 256, 256, 0, stream>>>(offs, counts, N);
    k_fill<<<(E + 255) / 256, 256, 0, stream>>>(dstp, srcp, counts, elist, ssorted, E);

    dim3 tgrid(HEADS, N / 128);

    // layer 1
    k_transform<<<tgrid, 256, 0, stream>>>(h, W1, as1, ad1, x, as_, adv);
    k_wered<<<1, 768, 0, stream>>>(We1, ae1, wr);
    k_logits<<<(E + 255) / 256, 256, 0, stream>>>(ea, wr, as_, adv, elist, ssorted,
                                                  dstp, lsort, E);
    k_aggregate<<<N, 256, 0, stream>>>(x, lsort, ssorted, offs, b1, lg1, lb1, z1);
    // layer 2
    k_transform<<<tgrid, 256, 0, stream>>>(z1, W2, as2, ad2, x, as_, adv);
    k_wered<<<1, 768, 0, stream>>>(We2, ae2, wr);
    k_logits<<<(E + 255) / 256, 256, 0, stream>>>(ea, wr, as_, adv, elist, ssorted,
                                                  dstp, lsort, E);
    k_aggregate<<<N, 256, 0, stream>>>(x, lsort, ssorted, offs, b2, lg2, lb2,
                                       (float*)d_out);
}

// Round 4
// 399.720 us; speedup vs baseline: 1.2450x; 1.0746x over previous
//
#include <hip/hip_runtime.h>
#include <math.h>

// Problem constants: N=32768 nodes, E=262144 edges, HID=64, HEADS=4
#define HIDDEN 64
#define HEADS 4
#define HC 256   // HEADS * HIDDEN

__device__ __forceinline__ unsigned short f2bf(float f) {
    unsigned int u = __float_as_uint(f);
    u += 0x7fffu + ((u >> 16) & 1u);   // round-to-nearest-even
    return (unsigned short)(u >> 16);
}

// ---------------- CSR build ----------------

__global__ void k_zero(int* p, int n) {
    int i = blockIdx.x * blockDim.x + threadIdx.x;
    if (i < n) p[i] = 0;
}

__global__ void k_count(const int* __restrict__ dst, int* __restrict__ counts, int E) {
    int e = blockIdx.x * blockDim.x + threadIdx.x;
    if (e < E) atomicAdd(&counts[dst[e]], 1);
}

// 1 block, 1024 threads, each handles 32 entries; writes offs AND cursor init.
__global__ void k_scan(const int* __restrict__ counts, int* __restrict__ offs,
                       int* __restrict__ cursor, int N) {
    __shared__ int sdata[1024];
    int t = threadIdx.x;
    int base = t * 32;
    int run = 0;
    for (int i = 0; i < 32; ++i) run += counts[base + i];
    sdata[t] = run;
    __syncthreads();
    for (int d = 1; d < 1024; d <<= 1) {
        int v = (t >= d) ? sdata[t - d] : 0;
        __syncthreads();
        sdata[t] += v;
        __syncthreads();
    }
    int running = (t == 0) ? 0 : sdata[t - 1];
    for (int i = 0; i < 32; ++i) {
        offs[base + i] = running;
        cursor[base + i] = running;
        running += counts[base + i];
    }
    if (t == 1023) offs[N] = running;
}

// fill: emit edge id, src and dst in dst-sorted order
__global__ void k_fill(const int* __restrict__ dst, const int* __restrict__ src,
                       int* __restrict__ cursor, int* __restrict__ elist,
                       int* __restrict__ ssorted, int* __restrict__ dsorted, int E) {
    int e = blockIdx.x * blockDim.x + threadIdx.x;
    if (e < E) {
        int d = dst[e];
        int p = atomicAdd(&cursor[d], 1);
        elist[p] = e;
        ssorted[p] = src[e];
        dsorted[p] = d;
    }
}

// ---------------- per-layer kernels ----------------

// Both layers' We_red in one launch. block 0 -> layer1 (wr[0..11]), block 1 -> layer2 (wr[16..27])
__global__ void k_wered2(const float* __restrict__ We1, const float* __restrict__ at1,
                         const float* __restrict__ We2, const float* __restrict__ at2,
                         float* __restrict__ wr) {
    const float* We = blockIdx.x ? We2 : We1;
    const float* at = blockIdx.x ? at2 : at1;
    float* o = wr + blockIdx.x * 16;
    int t = threadIdx.x;
    int w = t >> 6, lane = t & 63;
    int d = w >> 2, h = w & 3;
    float v = We[d * HC + h * HIDDEN + lane] * at[h * HIDDEN + lane];
    for (int off = 32; off > 0; off >>= 1) v += __shfl_down(v, off);
    if (lane == 0) o[d * HEADS + h] = v;
}

// LDS-tiled transform: x = z @ W (64 -> 256), bf16 x out, fused alpha_src/alpha_dst.
// blockIdx.x = head (64-col tile), blockIdx.y = 128-node chunk. 256 thr = 4 waves.
__global__ __launch_bounds__(256) void k_transform(const float* __restrict__ z,
                                                   const float* __restrict__ W,
                                                   const float* __restrict__ asw,
                                                   const float* __restrict__ adw,
                                                   unsigned short* __restrict__ xb,
                                                   float* __restrict__ as_,
                                                   float* __restrict__ ad_) {
    __shared__ float wlds[64 * 64];    // 16 KB: W[d][c] for this head
    __shared__ float zlds[128 * 64];   // 32 KB: z rows of this chunk
    int h = blockIdx.x;
    int chunk = blockIdx.y;
    int t = threadIdx.x;

    float4* wl4 = (float4*)wlds;
#pragma unroll
    for (int r = 0; r < 4; ++r) {
        int idx = t + 256 * r;             // 1024 float4 = 64x64 floats
        int d = idx >> 4, c4 = idx & 15;
        wl4[idx] = *(const float4*)&W[d * HC + h * HIDDEN + c4 * 4];
    }
    float4* zl4 = (float4*)zlds;
    const float4* zg4 = (const float4*)(z + (size_t)chunk * 128 * HIDDEN);
#pragma unroll
    for (int r = 0; r < 8; ++r) zl4[t + 256 * r] = zg4[t + 256 * r];
    __syncthreads();

    int w = t >> 6, lane = t & 63;
    float wcol[64];
#pragma unroll
    for (int d = 0; d < 64; ++d) wcol[d] = wlds[d * 64 + lane];
    float aw = asw[h * HIDDEN + lane], dw = adw[h * HIDDEN + lane];

    for (int nn = w; nn < 128; nn += 4) {
        const float4* zr = (const float4*)&zlds[nn * 64];
        float acc = 0.f;
#pragma unroll
        for (int d4 = 0; d4 < 16; ++d4) {
            float4 zv = zr[d4];
            acc += zv.x * wcol[d4 * 4 + 0] + zv.y * wcol[d4 * 4 + 1]
                 + zv.z * wcol[d4 * 4 + 2] + zv.w * wcol[d4 * 4 + 3];
        }
        int n = chunk * 128 + nn;
        xb[(size_t)n * HC + h * HIDDEN + lane] = f2bf(acc);
        float vs = acc * aw, vd = acc * dw;
#pragma unroll
        for (int o = 32; o > 0; o >>= 1) {
            vs += __shfl_down(vs, o);
            vd += __shfl_down(vd, o);
        }
        if (lane == 0) {
            as_[n * HEADS + h] = vs;
            ad_[n * HEADS + h] = vd;
        }
    }
}

// Per-edge logits in dst-sorted order: lsort[p][h] = leakyrelu(as[src]+ad[dst]+ae)
__global__ __launch_bounds__(256) void k_logits(
        const float* __restrict__ ea, const float* __restrict__ wr,
        const float* __restrict__ as_, const float* __restrict__ ad_,
        const int* __restrict__ elist, const int* __restrict__ ssorted,
        const int* __restrict__ dsorted, float* __restrict__ lsort, int E) {
    int p = blockIdx.x * blockDim.x + threadIdx.x;
    if (p >= E) return;
    int e = elist[p], s = ssorted[p], d = dsorted[p];
    float a0 = ea[e * 3 + 0];
    float a1 = ea[e * 3 + 1];
    float a2 = ea[e * 3 + 2];
    float4 av = *(const float4*)&as_[s * 4];
    float4 dv = *(const float4*)&ad_[d * 4];
    float as4[4] = {av.x, av.y, av.z, av.w};
    float ad4[4] = {dv.x, dv.y, dv.z, dv.w};
#pragma unroll
    for (int h = 0; h < 4; ++h) {
        float lg = as4[h] + ad4[h] + a0 * wr[h] + a1 * wr[4 + h] + a2 * wr[8 + h];
        lsort[p * 4 + h] = (lg >= 0.f) ? lg : 0.2f * lg;
    }
}

// Per-node: segment softmax + 8-edge-parallel bf16 gather + head mean + bias
// + LayerNorm + SiLU. wave = head; lane = (edge-slot, channel-group).
__global__ __launch_bounds__(256) void k_aggregate(
        const unsigned short* __restrict__ xb, const float* __restrict__ lsort,
        const int* __restrict__ ssorted, const int* __restrict__ offs,
        const float* __restrict__ bias, const float* __restrict__ lng,
        const float* __restrict__ lnb, float* __restrict__ out) {
    __shared__ float sh[HEADS][HIDDEN];
    int n = blockIdx.x, t = threadIdx.x;
    int h = t >> 6, lane = t & 63;
    int beg = offs[n], deg = offs[n + 1] - beg;

    // softmax stats
    float m = -INFINITY;
    for (int i = lane; i < deg; i += 64) m = fmaxf(m, lsort[(beg + i) * 4 + h]);
#pragma unroll
    for (int o = 32; o > 0; o >>= 1) m = fmaxf(m, __shfl_xor(m, o));
    float ssum = 0.f;
    for (int i = lane; i < deg; i += 64) ssum += __expf(lsort[(beg + i) * 4 + h] - m);
#pragma unroll
    for (int o = 32; o > 0; o >>= 1) ssum += __shfl_xor(ssum, o);
    float winv = 1.f / (ssum + 1e-16f);

    // 8 edges x 8-channel groups per wave; one uint4 (8 bf16) per lane per trip
    int eslot = lane >> 3, c8 = lane & 7;
    float acc[8];
#pragma unroll
    for (int k = 0; k < 8; ++k) acc[k] = 0.f;
    for (int base0 = 0; base0 < deg; base0 += 8) {
        int i = base0 + eslot;
        float wgt = 0.f;
        int s = 0;
        if (i < deg) {
            wgt = __expf(lsort[(beg + i) * 4 + h] - m) * winv;
            s = ssorted[beg + i];
        }
        uint4 raw = *(const uint4*)&xb[(size_t)s * HC + h * HIDDEN + c8 * 8];
        unsigned int u[4] = {raw.x, raw.y, raw.z, raw.w};
#pragma unroll
        for (int k = 0; k < 4; ++k) {
            float lo = __uint_as_float(u[k] << 16);
            float hi = __uint_as_float(u[k] & 0xffff0000u);
            acc[2 * k + 0] += wgt * lo;
            acc[2 * k + 1] += wgt * hi;
        }
    }
#pragma unroll
    for (int o = 8; o < 64; o <<= 1)
#pragma unroll
        for (int k = 0; k < 8; ++k) acc[k] += __shfl_xor(acc[k], o);
    if (lane < 8) {
#pragma unroll
        for (int k = 0; k < 8; ++k) sh[h][c8 * 8 + k] = acc[k];
    }
    __syncthreads();

    // epilogue on wave 0: head mean + bias + LayerNorm + SiLU
    if (t < HIDDEN) {
        int c = t;
        float u = (sh[0][c] + sh[1][c] + sh[2][c] + sh[3][c]) * 0.25f + bias[c];
        float mu = u;
#pragma unroll
        for (int o = 32; o > 0; o >>= 1) mu += __shfl_xor(mu, o);
        mu *= (1.f / 64.f);
        float dlt = u - mu;
        float var = dlt * dlt;
#pragma unroll
        for (int o = 32; o > 0; o >>= 1) var += __shfl_xor(var, o);
        var *= (1.f / 64.f);
        float y = dlt * rsqrtf(var + 1e-5f) * lng[c] + lnb[c];
        float r = y / (1.f + __expf(-y));  // silu
        out[n * HIDDEN + c] = r;
    }
}

// ---------------- launch ----------------

extern "C" void kernel_launch(void* const* d_in, const int* in_sizes, int n_in,
                              void* d_out, int out_size, void* d_ws, size_t ws_size,
                              hipStream_t stream) {
    const float* h   = (const float*)d_in[1];
    const int*   ei  = (const int*)d_in[2];
    const float* ea  = (const float*)d_in[3];
    const float* W1  = (const float*)d_in[4];
    const float* We1 = (const float*)d_in[5];
    const float* as1 = (const float*)d_in[6];
    const float* ad1 = (const float*)d_in[7];
    const float* ae1 = (const float*)d_in[8];
    const float* b1  = (const float*)d_in[9];
    const float* lg1 = (const float*)d_in[10];
    const float* lb1 = (const float*)d_in[11];
    const float* W2  = (const float*)d_in[12];
    const float* We2 = (const float*)d_in[13];
    const float* as2 = (const float*)d_in[14];
    const float* ad2 = (const float*)d_in[15];
    const float* ae2 = (const float*)d_in[16];
    const float* b2  = (const float*)d_in[17];
    const float* lg2 = (const float*)d_in[18];
    const float* lb2 = (const float*)d_in[19];

    const int N = in_sizes[1] / HIDDEN;   // 32768
    const int E = in_sizes[2] / 2;        // 262144
    const int* srcp = ei;
    const int* dstp = ei + E;

    // workspace layout (all regions fully written before read)
    char* w = (char*)d_ws;
    unsigned short* xb = (unsigned short*)w; w += (size_t)N * HC * 2;  // 16.75 MB
    float* as_    = (float*)w;  w += (size_t)N * HEADS * 4;
    float* adv    = (float*)w;  w += (size_t)N * HEADS * 4;
    float* lsort  = (float*)w;  w += (size_t)E * 4 * 4;         // 4 MB
    float* z1     = (float*)w;  w += (size_t)N * HIDDEN * 4;    // 8 MB
    float* wr     = (float*)w;  w += 128;
    int* counts   = (int*)w;    w += (size_t)N * 4;
    int* cursor   = (int*)w;    w += (size_t)N * 4;
    int* offs     = (int*)w;    w += (size_t)(N + 1) * 4 + 124; // pad to 16B
    int* elist    = (int*)w;    w += (size_t)E * 4;
    int* ssorted  = (int*)w;    w += (size_t)E * 4;
    int* dsorted  = (int*)w;    w += (size_t)E * 4;

    // CSR by dst (shared across both layers)
    k_zero<<<(N + 255) / 256, 256, 0, stream>>>(counts, N);
    k_count<<<(E + 255) / 256, 256, 0, stream>>>(dstp, counts, E);
    k_scan<<<1, 1024, 0, stream>>>(counts, offs, cursor, N);
    k_fill<<<(E + 255) / 256, 256, 0, stream>>>(dstp, srcp, cursor, elist,
                                                ssorted, dsorted, E);
    k_wered2<<<2, 768, 0, stream>>>(We1, ae1, We2, ae2, wr);

    dim3 tgrid(HEADS, N / 128);

    // layer 1
    k_transform<<<tgrid, 256, 0, stream>>>(h, W1, as1, ad1, xb, as_, adv);
    k_logits<<<(E + 255) / 256, 256, 0, stream>>>(ea, wr, as_, adv, elist, ssorted,
                                                  dsorted, lsort, E);
    k_aggregate<<<N, 256, 0, stream>>>(xb, lsort, ssorted, offs, b1, lg1, lb1, z1);
    // layer 2
    k_transform<<<tgrid, 256, 0, stream>>>(z1, W2, as2, ad2, xb, as_, adv);
    k_logits<<<(E + 255) / 256, 256, 0, stream>>>(ea, wr + 16, as_, adv, elist, ssorted,
                                                  dsorted, lsort, E);
    k_aggregate<<<N, 256, 0, stream>>>(xb, lsort, ssorted, offs, b2, lg2, lb2,
                                       (float*)d_out);
}

// Round 5
// 323.411 us; speedup vs baseline: 1.5388x; 1.2360x over previous
//
#include <hip/hip_runtime.h>
#include <math.h>

// Problem constants: N=32768 nodes, E=262144 edges, HID=64, HEADS=4
#define HIDDEN 64
#define HEADS 4
#define HC 256   // HEADS * HIDDEN

__device__ __forceinline__ unsigned short f2bf(float f) {
    unsigned int u = __float_as_uint(f);
    u += 0x7fffu + ((u >> 16) & 1u);   // round-to-nearest-even
    return (unsigned short)(u >> 16);
}

// ---------------- CSR build ----------------

__global__ void k_zero(int* p, int n) {
    int i = blockIdx.x * blockDim.x + threadIdx.x;
    if (i < n) p[i] = 0;
}

__global__ void k_count(const int* __restrict__ dst, int* __restrict__ counts, int E) {
    int e = blockIdx.x * blockDim.x + threadIdx.x;
    if (e < E) atomicAdd(&counts[dst[e]], 1);
}

// 128 blocks x 256: block sums of counts
__global__ __launch_bounds__(256) void k_bsum(const int* __restrict__ counts,
                                              int* __restrict__ bsum) {
    __shared__ int sd[256];
    int b = blockIdx.x, t = threadIdx.x;
    sd[t] = counts[b * 256 + t];
    __syncthreads();
#pragma unroll
    for (int d = 128; d > 0; d >>= 1) {
        if (t < d) sd[t] += sd[t + d];
        __syncthreads();
    }
    if (t == 0) bsum[b] = sd[0];
}

// 1 block x 128: exclusive scan of block sums; also writes offs[N]=total
__global__ void k_bscan(const int* __restrict__ bsum, int* __restrict__ bpre,
                        int* __restrict__ offs, int N) {
    __shared__ int sd[128];
    int t = threadIdx.x;
    sd[t] = bsum[t];
    __syncthreads();
    for (int d = 1; d < 128; d <<= 1) {
        int v = (t >= d) ? sd[t - d] : 0;
        __syncthreads();
        sd[t] += v;
        __syncthreads();
    }
    bpre[t] = sd[t] - bsum[t];   // exclusive
    if (t == 127) offs[N] = sd[127];
}

// 128 blocks x 256: local exclusive scan + block prefix -> offs, cursor
__global__ __launch_bounds__(256) void k_scanc(const int* __restrict__ counts,
                                               const int* __restrict__ bpre,
                                               int* __restrict__ offs,
                                               int* __restrict__ cursor) {
    __shared__ int sd[256];
    int b = blockIdx.x, t = threadIdx.x;
    int c = counts[b * 256 + t];
    sd[t] = c;
    __syncthreads();
    for (int d = 1; d < 256; d <<= 1) {
        int v = (t >= d) ? sd[t - d] : 0;
        __syncthreads();
        sd[t] += v;
        __syncthreads();
    }
    int off = bpre[b] + sd[t] - c;   // exclusive
    offs[b * 256 + t] = off;
    cursor[b * 256 + t] = off;
}

// fill: single 8B scatter per edge: es[p] = (edge id, src)
__global__ void k_fill(const int* __restrict__ dst, const int* __restrict__ src,
                       int* __restrict__ cursor, int2* __restrict__ es, int E) {
    int e = blockIdx.x * blockDim.x + threadIdx.x;
    if (e < E) {
        int p = atomicAdd(&cursor[dst[e]], 1);
        es[p] = make_int2(e, src[e]);
    }
}

// ---------------- per-layer kernels ----------------

// Both layers' We_red in one launch. block 0 -> wr[0..11], block 1 -> wr[16..27]
__global__ void k_wered2(const float* __restrict__ We1, const float* __restrict__ at1,
                         const float* __restrict__ We2, const float* __restrict__ at2,
                         float* __restrict__ wr) {
    const float* We = blockIdx.x ? We2 : We1;
    const float* at = blockIdx.x ? at2 : at1;
    float* o = wr + blockIdx.x * 16;
    int t = threadIdx.x;
    int w = t >> 6, lane = t & 63;
    int d = w >> 2, h = w & 3;
    float v = We[d * HC + h * HIDDEN + lane] * at[h * HIDDEN + lane];
    for (int off = 32; off > 0; off >>= 1) v += __shfl_down(v, off);
    if (lane == 0) o[d * HEADS + h] = v;
}

// LDS-tiled transform: x = z @ W (64 -> 256), bf16 x out, fused alpha_src/alpha_dst.
// blockIdx.x = head (64-col tile), blockIdx.y = 128-node chunk. 256 thr = 4 waves.
__global__ __launch_bounds__(256) void k_transform(const float* __restrict__ z,
                                                   const float* __restrict__ W,
                                                   const float* __restrict__ asw,
                                                   const float* __restrict__ adw,
                                                   unsigned short* __restrict__ xb,
                                                   float* __restrict__ as_,
                                                   float* __restrict__ ad_) {
    __shared__ float wlds[64 * 64];    // 16 KB: W[d][c] for this head
    __shared__ float zlds[128 * 64];   // 32 KB: z rows of this chunk
    int h = blockIdx.x;
    int chunk = blockIdx.y;
    int t = threadIdx.x;

    float4* wl4 = (float4*)wlds;
#pragma unroll
    for (int r = 0; r < 4; ++r) {
        int idx = t + 256 * r;             // 1024 float4 = 64x64 floats
        int d = idx >> 4, c4 = idx & 15;
        wl4[idx] = *(const float4*)&W[d * HC + h * HIDDEN + c4 * 4];
    }
    float4* zl4 = (float4*)zlds;
    const float4* zg4 = (const float4*)(z + (size_t)chunk * 128 * HIDDEN);
#pragma unroll
    for (int r = 0; r < 8; ++r) zl4[t + 256 * r] = zg4[t + 256 * r];
    __syncthreads();

    int w = t >> 6, lane = t & 63;
    float wcol[64];
#pragma unroll
    for (int d = 0; d < 64; ++d) wcol[d] = wlds[d * 64 + lane];
    float aw = asw[h * HIDDEN + lane], dw = adw[h * HIDDEN + lane];

    for (int nn = w; nn < 128; nn += 4) {
        const float4* zr = (const float4*)&zlds[nn * 64];
        float acc = 0.f;
#pragma unroll
        for (int d4 = 0; d4 < 16; ++d4) {
            float4 zv = zr[d4];
            acc += zv.x * wcol[d4 * 4 + 0] + zv.y * wcol[d4 * 4 + 1]
                 + zv.z * wcol[d4 * 4 + 2] + zv.w * wcol[d4 * 4 + 3];
        }
        int n = chunk * 128 + nn;
        xb[(size_t)n * HC + h * HIDDEN + lane] = f2bf(acc);
        float vs = acc * aw, vd = acc * dw;
#pragma unroll
        for (int o = 32; o > 0; o >>= 1) {
            vs += __shfl_down(vs, o);
            vd += __shfl_down(vd, o);
        }
        if (lane == 0) {
            as_[n * HEADS + h] = vs;
            ad_[n * HEADS + h] = vd;
        }
    }
}

// Partial logits in dst-sorted order (NO dst term, NO leaky-relu yet):
// lspart[p][h] = as_[src][h] + edge_attr[e] @ wr[:,h]
__global__ __launch_bounds__(256) void k_logits(
        const float* __restrict__ ea, const float* __restrict__ wr,
        const float* __restrict__ as_, const int2* __restrict__ es,
        float* __restrict__ lspart, int E) {
    int p = blockIdx.x * blockDim.x + threadIdx.x;
    if (p >= E) return;
    int2 epair = es[p];
    int e = epair.x, s = epair.y;
    float a0 = ea[e * 3 + 0];
    float a1 = ea[e * 3 + 1];
    float a2 = ea[e * 3 + 2];
    float4 av = *(const float4*)&as_[s * 4];
    float as4[4] = {av.x, av.y, av.z, av.w};
    float o4[4];
#pragma unroll
    for (int h = 0; h < 4; ++h)
        o4[h] = as4[h] + a0 * wr[h] + a1 * wr[4 + h] + a2 * wr[8 + h];
    *(float4*)&lspart[p * 4] = make_float4(o4[0], o4[1], o4[2], o4[3]);
}

// Wave-per-node aggregate: softmax + bf16 gather + head mean + LN + SiLU,
// all in-register (no LDS, no barriers). lane = h*16 + e*8 + g:
//   h = head (4), e = edge slot (2), g = 8-channel group (8).
__global__ __launch_bounds__(256) void k_aggregate(
        const unsigned short* __restrict__ xb, const float* __restrict__ lspart,
        const int2* __restrict__ es, const int* __restrict__ offs,
        const float* __restrict__ ad_,
        const float* __restrict__ bias, const float* __restrict__ lng,
        const float* __restrict__ lnb, float* __restrict__ out, int N) {
    int lane = threadIdx.x & 63;
    int h = lane >> 4, sub = lane & 15;
    int e = (lane >> 3) & 1, g = lane & 7;
    int wid = blockIdx.x * 4 + (threadIdx.x >> 6);
    int nwaves = gridDim.x * 4;

    float bs[8], gm[8], bt[8];
#pragma unroll
    for (int k = 0; k < 8; ++k) {
        bs[k] = bias[g * 8 + k];
        gm[k] = lng[g * 8 + k];
        bt[k] = lnb[g * 8 + k];
    }

    for (int n = wid; n < N; n += nwaves) {
        int beg = offs[n], deg = offs[n + 1] - beg;
        float ad4 = ad_[n * 4 + h];

        // pass 1: max over lrelu(lspart + ad)
        float m = -INFINITY;
        for (int i = sub; i < deg; i += 16) {
            float lg = lspart[(beg + i) * 4 + h] + ad4;
            lg = (lg >= 0.f) ? lg : 0.2f * lg;
            m = fmaxf(m, lg);
        }
#pragma unroll
        for (int o = 1; o < 16; o <<= 1) m = fmaxf(m, __shfl_xor(m, o));
        // pass 2: sum
        float ssum = 0.f;
        for (int i = sub; i < deg; i += 16) {
            float lg = lspart[(beg + i) * 4 + h] + ad4;
            lg = (lg >= 0.f) ? lg : 0.2f * lg;
            ssum += __expf(lg - m);
        }
#pragma unroll
        for (int o = 1; o < 16; o <<= 1) ssum += __shfl_xor(ssum, o);
        float winv = 1.f / (ssum + 1e-16f);

        // gather: 4 edges per trip (2 per edge-slot), 2 independent loads/lane
        float acc[8];
#pragma unroll
        for (int k = 0; k < 8; ++k) acc[k] = 0.f;
        for (int i0 = 0; i0 < deg; i0 += 4) {
#pragma unroll
            for (int j = 0; j < 2; ++j) {
                int i = i0 + e * 2 + j;
                float wgt = 0.f;
                int s = 0;
                if (i < deg) {
                    float lg = lspart[(beg + i) * 4 + h] + ad4;
                    lg = (lg >= 0.f) ? lg : 0.2f * lg;
                    wgt = __expf(lg - m) * winv;
                    s = es[beg + i].y;
                }
                uint4 raw = *(const uint4*)&xb[(size_t)s * HC + h * HIDDEN + g * 8];
                unsigned int u[4] = {raw.x, raw.y, raw.z, raw.w};
#pragma unroll
                for (int k = 0; k < 4; ++k) {
                    acc[2 * k + 0] += wgt * __uint_as_float(u[k] << 16);
                    acc[2 * k + 1] += wgt * __uint_as_float(u[k] & 0xffff0000u);
                }
            }
        }
        // reduce over edge slot (bit 3) and heads (bits 4,5)
#pragma unroll
        for (int o = 8; o < 64; o <<= 1)
#pragma unroll
            for (int k = 0; k < 8; ++k) acc[k] += __shfl_xor(acc[k], o);

        // epilogue (all lanes redundant; lanes 0..7 store)
        float u8[8], s1 = 0.f;
#pragma unroll
        for (int k = 0; k < 8; ++k) {
            u8[k] = acc[k] * 0.25f + bs[k];
            s1 += u8[k];
        }
#pragma unroll
        for (int o = 1; o < 8; o <<= 1) s1 += __shfl_xor(s1, o);
        float mu = s1 * (1.f / 64.f);
        float s2 = 0.f;
#pragma unroll
        for (int k = 0; k < 8; ++k) {
            float d = u8[k] - mu;
            s2 += d * d;
        }
#pragma unroll
        for (int o = 1; o < 8; o <<= 1) s2 += __shfl_xor(s2, o);
        float rstd = rsqrtf(s2 * (1.f / 64.f) + 1e-5f);
        float r[8];
#pragma unroll
        for (int k = 0; k < 8; ++k) {
            float y = (u8[k] - mu) * rstd * gm[k] + bt[k];
            r[k] = y / (1.f + __expf(-y));
        }
        if (lane < 8) {
            float4* o4 = (float4*)&out[(size_t)n * HIDDEN + g * 8];
            o4[0] = make_float4(r[0], r[1], r[2], r[3]);
            o4[1] = make_float4(r[4], r[5], r[6], r[7]);
        }
    }
}

// ---------------- launch ----------------

extern "C" void kernel_launch(void* const* d_in, const int* in_sizes, int n_in,
                              void* d_out, int out_size, void* d_ws, size_t ws_size,
                              hipStream_t stream) {
    const float* h   = (const float*)d_in[1];
    const int*   ei  = (const int*)d_in[2];
    const float* ea  = (const float*)d_in[3];
    const float* W1  = (const float*)d_in[4];
    const float* We1 = (const float*)d_in[5];
    const float* as1 = (const float*)d_in[6];
    const float* ad1 = (const float*)d_in[7];
    const float* ae1 = (const float*)d_in[8];
    const float* b1  = (const float*)d_in[9];
    const float* lg1 = (const float*)d_in[10];
    const float* lb1 = (const float*)d_in[11];
    const float* W2  = (const float*)d_in[12];
    const float* We2 = (const float*)d_in[13];
    const float* as2 = (const float*)d_in[14];
    const float* ad2 = (const float*)d_in[15];
    const float* ae2 = (const float*)d_in[16];
    const float* b2  = (const float*)d_in[17];
    const float* lg2 = (const float*)d_in[18];
    const float* lb2 = (const float*)d_in[19];

    const int N = in_sizes[1] / HIDDEN;   // 32768
    const int E = in_sizes[2] / 2;        // 262144
    const int* srcp = ei;
    const int* dstp = ei + E;

    // workspace layout (all regions fully written before read)
    char* w = (char*)d_ws;
    unsigned short* xb = (unsigned short*)w; w += (size_t)N * HC * 2;  // 16.75 MB
    float* as_    = (float*)w;  w += (size_t)N * HEADS * 4;
    float* adv    = (float*)w;  w += (size_t)N * HEADS * 4;
    float* lspart = (float*)w;  w += (size_t)E * 4 * 4;         // 4 MB
    float* z1     = (float*)w;  w += (size_t)N * HIDDEN * 4;    // 8 MB
    float* wr     = (float*)w;  w += 128;
    int* counts   = (int*)w;    w += (size_t)N * 4;
    int* cursor   = (int*)w;    w += (size_t)N * 4;
    int* offs     = (int*)w;    w += (size_t)(N + 1) * 4 + 124; // pad to 16B
    int* bsum     = (int*)w;    w += 128 * 4;
    int* bpre     = (int*)w;    w += 128 * 4;
    int2* es      = (int2*)w;   w += (size_t)E * 8;

    // CSR by dst (shared across both layers)
    k_zero<<<(N + 255) / 256, 256, 0, stream>>>(counts, N);
    k_count<<<(E + 255) / 256, 256, 0, stream>>>(dstp, counts, E);
    k_bsum<<<N / 256, 256, 0, stream>>>(counts, bsum);
    k_bscan<<<1, 128, 0, stream>>>(bsum, bpre, offs, N);
    k_scanc<<<N / 256, 256, 0, stream>>>(counts, bpre, offs, cursor);
    k_fill<<<(E + 255) / 256, 256, 0, stream>>>(dstp, srcp, cursor, es, E);
    k_wered2<<<2, 768, 0, stream>>>(We1, ae1, We2, ae2, wr);

    dim3 tgrid(HEADS, N / 128);

    // layer 1
    k_transform<<<tgrid, 256, 0, stream>>>(h, W1, as1, ad1, xb, as_, adv);
    k_logits<<<(E + 255) / 256, 256, 0, stream>>>(ea, wr, as_, es, lspart, E);
    k_aggregate<<<4096, 256, 0, stream>>>(xb, lspart, es, offs, adv,
                                          b1, lg1, lb1, z1, N);
    // layer 2
    k_transform<<<tgrid, 256, 0, stream>>>(z1, W2, as2, ad2, xb, as_, adv);
    k_logits<<<(E + 255) / 256, 256, 0, stream>>>(ea, wr + 16, as_, es, lspart, E);
    k_aggregate<<<4096, 256, 0, stream>>>(xb, lspart, es, offs, adv,
                                          b2, lg2, lb2, (float*)d_out, N);
}

// Round 6
// 265.094 us; speedup vs baseline: 1.8773x; 1.2200x over previous
//
#include <hip/hip_runtime.h>
#include <math.h>

// Problem constants: N=32768 nodes, E=262144 edges, HID=64, HEADS=4
#define HIDDEN 64
#define HEADS 4
#define HC 256   // HEADS * HIDDEN

typedef __attribute__((ext_vector_type(8))) short short8;   // 8 bf16 (4 VGPRs)
typedef __attribute__((ext_vector_type(4))) float f32x4;    // MFMA acc

__device__ __forceinline__ unsigned short f2bf(float f) {
    unsigned int u = __float_as_uint(f);
    u += 0x7fffu + ((u >> 16) & 1u);   // round-to-nearest-even
    return (unsigned short)(u >> 16);
}

// ---------------- CSR build ----------------

__global__ void k_zero(int* p, int n) {
    int i = blockIdx.x * blockDim.x + threadIdx.x;
    if (i < n) p[i] = 0;
}

__global__ void k_count(const int* __restrict__ dst, int* __restrict__ counts, int E) {
    int e = blockIdx.x * blockDim.x + threadIdx.x;
    if (e < E) atomicAdd(&counts[dst[e]], 1);
}

// 128 blocks x 256: block sums of counts
__global__ __launch_bounds__(256) void k_bsum(const int* __restrict__ counts,
                                              int* __restrict__ bsum) {
    __shared__ int sd[256];
    int b = blockIdx.x, t = threadIdx.x;
    sd[t] = counts[b * 256 + t];
    __syncthreads();
#pragma unroll
    for (int d = 128; d > 0; d >>= 1) {
        if (t < d) sd[t] += sd[t + d];
        __syncthreads();
    }
    if (t == 0) bsum[b] = sd[0];
}

// 1 block x 128: exclusive scan of block sums; also writes offs[N]=total
__global__ void k_bscan(const int* __restrict__ bsum, int* __restrict__ bpre,
                        int* __restrict__ offs, int N) {
    __shared__ int sd[128];
    int t = threadIdx.x;
    sd[t] = bsum[t];
    __syncthreads();
    for (int d = 1; d < 128; d <<= 1) {
        int v = (t >= d) ? sd[t - d] : 0;
        __syncthreads();
        sd[t] += v;
        __syncthreads();
    }
    bpre[t] = sd[t] - bsum[t];   // exclusive
    if (t == 127) offs[N] = sd[127];
}

// 128 blocks x 256: local exclusive scan + block prefix -> offs, cursor
__global__ __launch_bounds__(256) void k_scanc(const int* __restrict__ counts,
                                               const int* __restrict__ bpre,
                                               int* __restrict__ offs,
                                               int* __restrict__ cursor) {
    __shared__ int sd[256];
    int b = blockIdx.x, t = threadIdx.x;
    int c = counts[b * 256 + t];
    sd[t] = c;
    __syncthreads();
    for (int d = 1; d < 256; d <<= 1) {
        int v = (t >= d) ? sd[t - d] : 0;
        __syncthreads();
        sd[t] += v;
        __syncthreads();
    }
    int off = bpre[b] + sd[t] - c;   // exclusive
    offs[b * 256 + t] = off;
    cursor[b * 256 + t] = off;
}

// fill: single 8B scatter per edge: es[p] = (edge id, src)
__global__ void k_fill(const int* __restrict__ dst, const int* __restrict__ src,
                       int* __restrict__ cursor, int2* __restrict__ es, int E) {
    int e = blockIdx.x * blockDim.x + threadIdx.x;
    if (e < E) {
        int p = atomicAdd(&cursor[dst[e]], 1);
        es[p] = make_int2(e, src[e]);
    }
}

// ---------------- prep: bf16 conversions ----------------
// blocks 0..2047: zb = bf16(h), 4 elems/thread.
// blocks 2048..2111: wt1/wt2[c*64+k] = bf16(W[k*256+c]) (transposed, both layers)
__global__ __launch_bounds__(256) void k_prep(const float* __restrict__ h,
                                              const float* __restrict__ W1f,
                                              const float* __restrict__ W2f,
                                              ushort* __restrict__ zb,
                                              ushort* __restrict__ wt1,
                                              ushort* __restrict__ wt2) {
    int i = blockIdx.x * 256 + threadIdx.x;
    if (blockIdx.x < 2048) {
        float4 v = ((const float4*)h)[i];
        ushort4 o;
        o.x = f2bf(v.x); o.y = f2bf(v.y); o.z = f2bf(v.z); o.w = f2bf(v.w);
        ((ushort4*)zb)[i] = o;
    } else {
        int j = i - 2048 * 256;     // 0..16383
        if (j < 16384) {
            int c = j >> 6, k = j & 63;
            wt1[j] = f2bf(W1f[k * HC + c]);
            wt2[j] = f2bf(W2f[k * HC + c]);
        }
    }
}

// Both layers' We_red in one launch. block 0 -> wr[0..11], block 1 -> wr[16..27]
__global__ void k_wered2(const float* __restrict__ We1, const float* __restrict__ at1,
                         const float* __restrict__ We2, const float* __restrict__ at2,
                         float* __restrict__ wr) {
    const float* We = blockIdx.x ? We2 : We1;
    const float* at = blockIdx.x ? at2 : at1;
    float* o = wr + blockIdx.x * 16;
    int t = threadIdx.x;
    int w = t >> 6, lane = t & 63;
    int d = w >> 2, h = w & 3;
    float v = We[d * HC + h * HIDDEN + lane] * at[h * HIDDEN + lane];
    for (int off = 32; off > 0; off >>= 1) v += __shfl_down(v, off);
    if (lane == 0) o[d * HEADS + h] = v;
}

// ---------------- MFMA transform ----------------
// x = z @ W (64 -> 256) via mfma_f32_16x16x32_bf16, fused alpha_src/alpha_dst.
// Block = 64 rows (4 waves x 16 rows); per wave: 4 heads x 4 N-tiles x 2 MFMA.
// A frag: lane holds z[row0+ (lane&15)][quad*8 .. +8)      (quad = lane>>4)
// B frag: lane holds Wt[col0+(lane&15)][quad*8 .. +8)      (Wt = W transposed)
// C/D:    lane holds rows row0+quad*4+r (r=0..3), col col0+(lane&15)
__global__ __launch_bounds__(256) void k_tmfma(const ushort* __restrict__ zb,
                                               const ushort* __restrict__ wt,
                                               const float* __restrict__ asw,
                                               const float* __restrict__ adw,
                                               ushort* __restrict__ xb,
                                               float* __restrict__ as_,
                                               float* __restrict__ ad_) {
    int wave = threadIdx.x >> 6, lane = threadIdx.x & 63;
    int q = lane & 15, quad = lane >> 4;
    int row0 = blockIdx.x * 64 + wave * 16;

    const ushort* zrow = zb + (size_t)(row0 + q) * 64 + quad * 8;
    short8 a0 = *(const short8*)(zrow);
    short8 a1 = *(const short8*)(zrow + 32);

#pragma unroll
    for (int h = 0; h < 4; ++h) {
        float vs[4] = {0.f, 0.f, 0.f, 0.f};
        float vd[4] = {0.f, 0.f, 0.f, 0.f};
#pragma unroll
        for (int nt = 0; nt < 4; ++nt) {
            int col0 = h * 64 + nt * 16;
            const ushort* wrow = wt + (size_t)(col0 + q) * 64 + quad * 8;
            short8 b0 = *(const short8*)(wrow);
            short8 b1 = *(const short8*)(wrow + 32);
            f32x4 acc = {0.f, 0.f, 0.f, 0.f};
            acc = __builtin_amdgcn_mfma_f32_16x16x32_bf16(a0, b0, acc, 0, 0, 0);
            acc = __builtin_amdgcn_mfma_f32_16x16x32_bf16(a1, b1, acc, 0, 0, 0);
            int c = col0 + q;
            float aw = asw[c], dw = adw[c];
#pragma unroll
            for (int r = 0; r < 4; ++r) {
                float v = acc[r];
                xb[(size_t)(row0 + quad * 4 + r) * HC + c] = f2bf(v);
                vs[r] += v * aw;
                vd[r] += v * dw;
            }
        }
        // reduce over the 16 lanes of this quad-group (cols of the head)
#pragma unroll
        for (int o = 1; o < 16; o <<= 1) {
#pragma unroll
            for (int r = 0; r < 4; ++r) {
                vs[r] += __shfl_xor(vs[r], o);
                vd[r] += __shfl_xor(vd[r], o);
            }
        }
        if (q < 4) {
            int n = row0 + quad * 4 + q;
            as_[n * 4 + h] = vs[q];
            ad_[n * 4 + h] = vd[q];
        }
    }
}

// Partial logits in dst-sorted order (NO dst term, NO leaky-relu yet):
// lspart[p][h] = as_[src][h] + edge_attr[e] @ wr[:,h]
__global__ __launch_bounds__(256) void k_logits(
        const float* __restrict__ ea, const float* __restrict__ wr,
        const float* __restrict__ as_, const int2* __restrict__ es,
        float* __restrict__ lspart, int E) {
    int p = blockIdx.x * blockDim.x + threadIdx.x;
    if (p >= E) return;
    int2 epair = es[p];
    int e = epair.x, s = epair.y;
    float a0 = ea[e * 3 + 0];
    float a1 = ea[e * 3 + 1];
    float a2 = ea[e * 3 + 2];
    float4 av = *(const float4*)&as_[s * 4];
    float as4[4] = {av.x, av.y, av.z, av.w};
    float o4[4];
#pragma unroll
    for (int h = 0; h < 4; ++h)
        o4[h] = as4[h] + a0 * wr[h] + a1 * wr[4 + h] + a2 * wr[8 + h];
    *(float4*)&lspart[p * 4] = make_float4(o4[0], o4[1], o4[2], o4[3]);
}

// Wave-per-node aggregate: softmax + bf16 gather + head mean + LN + SiLU,
// all in-register. lane = h*16 + e*8 + g. Output: fp32 (outf) or bf16 (outb).
__global__ __launch_bounds__(256) void k_aggregate(
        const unsigned short* __restrict__ xb, const float* __restrict__ lspart,
        const int2* __restrict__ es, const int* __restrict__ offs,
        const float* __restrict__ ad_,
        const float* __restrict__ bias, const float* __restrict__ lng,
        const float* __restrict__ lnb, float* __restrict__ outf,
        ushort* __restrict__ outb, int N) {
    int lane = threadIdx.x & 63;
    int h = lane >> 4, sub = lane & 15;
    int e = (lane >> 3) & 1, g = lane & 7;
    int wid = blockIdx.x * 4 + (threadIdx.x >> 6);
    int nwaves = gridDim.x * 4;

    float bs[8], gm[8], bt[8];
#pragma unroll
    for (int k = 0; k < 8; ++k) {
        bs[k] = bias[g * 8 + k];
        gm[k] = lng[g * 8 + k];
        bt[k] = lnb[g * 8 + k];
    }

    for (int n = wid; n < N; n += nwaves) {
        int beg = offs[n], deg = offs[n + 1] - beg;
        float ad4 = ad_[n * 4 + h];

        // pass 1: max over lrelu(lspart + ad)
        float m = -INFINITY;
        for (int i = sub; i < deg; i += 16) {
            float lg = lspart[(beg + i) * 4 + h] + ad4;
            lg = (lg >= 0.f) ? lg : 0.2f * lg;
            m = fmaxf(m, lg);
        }
#pragma unroll
        for (int o = 1; o < 16; o <<= 1) m = fmaxf(m, __shfl_xor(m, o));
        // pass 2: sum
        float ssum = 0.f;
        for (int i = sub; i < deg; i += 16) {
            float lg = lspart[(beg + i) * 4 + h] + ad4;
            lg = (lg >= 0.f) ? lg : 0.2f * lg;
            ssum += __expf(lg - m);
        }
#pragma unroll
        for (int o = 1; o < 16; o <<= 1) ssum += __shfl_xor(ssum, o);
        float winv = 1.f / (ssum + 1e-16f);

        // gather: 4 edges per trip (2 per edge-slot), 2 independent loads/lane
        float acc[8];
#pragma unroll
        for (int k = 0; k < 8; ++k) acc[k] = 0.f;
        for (int i0 = 0; i0 < deg; i0 += 4) {
#pragma unroll
            for (int j = 0; j < 2; ++j) {
                int i = i0 + e * 2 + j;
                float wgt = 0.f;
                int s = 0;
                if (i < deg) {
                    float lg = lspart[(beg + i) * 4 + h] + ad4;
                    lg = (lg >= 0.f) ? lg : 0.2f * lg;
                    wgt = __expf(lg - m) * winv;
                    s = es[beg + i].y;
                }
                uint4 raw = *(const uint4*)&xb[(size_t)s * HC + h * HIDDEN + g * 8];
                unsigned int u[4] = {raw.x, raw.y, raw.z, raw.w};
#pragma unroll
                for (int k = 0; k < 4; ++k) {
                    acc[2 * k + 0] += wgt * __uint_as_float(u[k] << 16);
                    acc[2 * k + 1] += wgt * __uint_as_float(u[k] & 0xffff0000u);
                }
            }
        }
        // reduce over edge slot (bit 3) and heads (bits 4,5)
#pragma unroll
        for (int o = 8; o < 64; o <<= 1)
#pragma unroll
            for (int k = 0; k < 8; ++k) acc[k] += __shfl_xor(acc[k], o);

        // epilogue (all lanes redundant; lanes 0..7 store)
        float u8[8], s1 = 0.f;
#pragma unroll
        for (int k = 0; k < 8; ++k) {
            u8[k] = acc[k] * 0.25f + bs[k];
            s1 += u8[k];
        }
#pragma unroll
        for (int o = 1; o < 8; o <<= 1) s1 += __shfl_xor(s1, o);
        float mu = s1 * (1.f / 64.f);
        float s2 = 0.f;
#pragma unroll
        for (int k = 0; k < 8; ++k) {
            float d = u8[k] - mu;
            s2 += d * d;
        }
#pragma unroll
        for (int o = 1; o < 8; o <<= 1) s2 += __shfl_xor(s2, o);
        float rstd = rsqrtf(s2 * (1.f / 64.f) + 1e-5f);
        float r[8];
#pragma unroll
        for (int k = 0; k < 8; ++k) {
            float y = (u8[k] - mu) * rstd * gm[k] + bt[k];
            r[k] = y / (1.f + __expf(-y));
        }
        if (lane < 8) {
            if (outb) {
                uint4 pk;
                pk.x = (unsigned)f2bf(r[0]) | ((unsigned)f2bf(r[1]) << 16);
                pk.y = (unsigned)f2bf(r[2]) | ((unsigned)f2bf(r[3]) << 16);
                pk.z = (unsigned)f2bf(r[4]) | ((unsigned)f2bf(r[5]) << 16);
                pk.w = (unsigned)f2bf(r[6]) | ((unsigned)f2bf(r[7]) << 16);
                *(uint4*)&outb[(size_t)n * HIDDEN + g * 8] = pk;
            } else {
                float4* o4 = (float4*)&outf[(size_t)n * HIDDEN + g * 8];
                o4[0] = make_float4(r[0], r[1], r[2], r[3]);
                o4[1] = make_float4(r[4], r[5], r[6], r[7]);
            }
        }
    }
}

// ---------------- launch ----------------

extern "C" void kernel_launch(void* const* d_in, const int* in_sizes, int n_in,
                              void* d_out, int out_size, void* d_ws, size_t ws_size,
                              hipStream_t stream) {
    const float* h   = (const float*)d_in[1];
    const int*   ei  = (const int*)d_in[2];
    const float* ea  = (const float*)d_in[3];
    const float* W1  = (const float*)d_in[4];
    const float* We1 = (const float*)d_in[5];
    const float* as1 = (const float*)d_in[6];
    const float* ad1 = (const float*)d_in[7];
    const float* ae1 = (const float*)d_in[8];
    const float* b1  = (const float*)d_in[9];
    const float* lg1 = (const float*)d_in[10];
    const float* lb1 = (const float*)d_in[11];
    const float* W2  = (const float*)d_in[12];
    const float* We2 = (const float*)d_in[13];
    const float* as2 = (const float*)d_in[14];
    const float* ad2 = (const float*)d_in[15];
    const float* ae2 = (const float*)d_in[16];
    const float* b2  = (const float*)d_in[17];
    const float* lg2 = (const float*)d_in[18];
    const float* lb2 = (const float*)d_in[19];

    const int N = in_sizes[1] / HIDDEN;   // 32768
    const int E = in_sizes[2] / 2;        // 262144
    const int* srcp = ei;
    const int* dstp = ei + E;

    // workspace layout (all regions fully written before read)
    char* w = (char*)d_ws;
    ushort* xb    = (ushort*)w; w += (size_t)N * HC * 2;       // 16.75 MB
    ushort* zb    = (ushort*)w; w += (size_t)N * HIDDEN * 2;   // 4 MB
    float* as_    = (float*)w;  w += (size_t)N * HEADS * 4;
    float* adv    = (float*)w;  w += (size_t)N * HEADS * 4;
    float* lspart = (float*)w;  w += (size_t)E * 4 * 4;        // 4 MB
    ushort* wt1   = (ushort*)w; w += 16384 * 2;
    ushort* wt2   = (ushort*)w; w += 16384 * 2;
    float* wr     = (float*)w;  w += 128;
    int* counts   = (int*)w;    w += (size_t)N * 4;
    int* cursor   = (int*)w;    w += (size_t)N * 4;
    int* offs     = (int*)w;    w += (size_t)(N + 1) * 4 + 124; // pad to 16B
    int* bsum     = (int*)w;    w += 128 * 4;
    int* bpre     = (int*)w;    w += 128 * 4;
    int2* es      = (int2*)w;   w += (size_t)E * 8;

    // CSR by dst (shared across both layers)
    k_zero<<<(N + 255) / 256, 256, 0, stream>>>(counts, N);
    k_count<<<(E + 255) / 256, 256, 0, stream>>>(dstp, counts, E);
    k_bsum<<<N / 256, 256, 0, stream>>>(counts, bsum);
    k_bscan<<<1, 128, 0, stream>>>(bsum, bpre, offs, N);
    k_scanc<<<N / 256, 256, 0, stream>>>(counts, bpre, offs, cursor);
    k_fill<<<(E + 255) / 256, 256, 0, stream>>>(dstp, srcp, cursor, es, E);
    k_prep<<<2112, 256, 0, stream>>>(h, W1, W2, zb, wt1, wt2);
    k_wered2<<<2, 768, 0, stream>>>(We1, ae1, We2, ae2, wr);

    // layer 1
    k_tmfma<<<N / 64, 256, 0, stream>>>(zb, wt1, as1, ad1, xb, as_, adv);
    k_logits<<<(E + 255) / 256, 256, 0, stream>>>(ea, wr, as_, es, lspart, E);
    k_aggregate<<<4096, 256, 0, stream>>>(xb, lspart, es, offs, adv,
                                          b1, lg1, lb1, nullptr, zb, N);
    // layer 2 (reads zb written by layer-1 aggregate)
    k_tmfma<<<N / 64, 256, 0, stream>>>(zb, wt2, as2, ad2, xb, as_, adv);
    k_logits<<<(E + 255) / 256, 256, 0, stream>>>(ea, wr + 16, as_, es, lspart, E);
    k_aggregate<<<4096, 256, 0, stream>>>(xb, lspart, es, offs, adv,
                                          b2, lg2, lb2, (float*)d_out, nullptr, N);
}

// Round 7
// 250.457 us; speedup vs baseline: 1.9870x; 1.0584x over previous
//
#include <hip/hip_runtime.h>
#include <math.h>

// Problem constants: N=32768 nodes, E=262144 edges, HID=64, HEADS=4
#define HIDDEN 64
#define HEADS 4
#define HC 256   // HEADS * HIDDEN

typedef __attribute__((ext_vector_type(8))) short short8;   // 8 bf16 (4 VGPRs)
typedef __attribute__((ext_vector_type(4))) float f32x4;    // MFMA acc

__device__ __forceinline__ unsigned short f2bf(float f) {
    unsigned int u = __float_as_uint(f);
    u += 0x7fffu + ((u >> 16) & 1u);   // round-to-nearest-even
    return (unsigned short)(u >> 16);
}

// ---------------- CSR build ----------------

__global__ void k_zero(int* p, int n) {
    int i = blockIdx.x * blockDim.x + threadIdx.x;
    if (i < n) p[i] = 0;
}

__global__ void k_count(const int* __restrict__ dst, int* __restrict__ counts, int E) {
    int e = blockIdx.x * blockDim.x + threadIdx.x;
    if (e < E) atomicAdd(&counts[dst[e]], 1);
}

// 128 blocks x 256: block sums of counts
__global__ __launch_bounds__(256) void k_bsum(const int* __restrict__ counts,
                                              int* __restrict__ bsum) {
    __shared__ int sd[256];
    int b = blockIdx.x, t = threadIdx.x;
    sd[t] = counts[b * 256 + t];
    __syncthreads();
#pragma unroll
    for (int d = 128; d > 0; d >>= 1) {
        if (t < d) sd[t] += sd[t + d];
        __syncthreads();
    }
    if (t == 0) bsum[b] = sd[0];
}

// 1 block x 128: exclusive scan of block sums; also writes offs[N]=total
__global__ void k_bscan(const int* __restrict__ bsum, int* __restrict__ bpre,
                        int* __restrict__ offs, int N) {
    __shared__ int sd[128];
    int t = threadIdx.x;
    sd[t] = bsum[t];
    __syncthreads();
    for (int d = 1; d < 128; d <<= 1) {
        int v = (t >= d) ? sd[t - d] : 0;
        __syncthreads();
        sd[t] += v;
        __syncthreads();
    }
    bpre[t] = sd[t] - bsum[t];   // exclusive
    if (t == 127) offs[N] = sd[127];
}

// 128 blocks x 256: local exclusive scan + block prefix -> offs, cursor
__global__ __launch_bounds__(256) void k_scanc(const int* __restrict__ counts,
                                               const int* __restrict__ bpre,
                                               int* __restrict__ offs,
                                               int* __restrict__ cursor) {
    __shared__ int sd[256];
    int b = blockIdx.x, t = threadIdx.x;
    int c = counts[b * 256 + t];
    sd[t] = c;
    __syncthreads();
    for (int d = 1; d < 256; d <<= 1) {
        int v = (t >= d) ? sd[t - d] : 0;
        __syncthreads();
        sd[t] += v;
        __syncthreads();
    }
    int off = bpre[b] + sd[t] - c;   // exclusive
    offs[b * 256 + t] = off;
    cursor[b * 256 + t] = off;
}

// fill: single 8B scatter per edge: es[p] = (edge id, src)
__global__ void k_fill(const int* __restrict__ dst, const int* __restrict__ src,
                       int* __restrict__ cursor, int2* __restrict__ es, int E) {
    int e = blockIdx.x * blockDim.x + threadIdx.x;
    if (e < E) {
        int p = atomicAdd(&cursor[dst[e]], 1);
        es[p] = make_int2(e, src[e]);
    }
}

// ---------------- prep: bf16 conversions + We reductions ----------------
// blocks [0,2048): zb = bf16(h), 4 floats/thread
// blocks [2048,2112): wt1/wt2[c*64+k] = bf16(W[k*256+c]) (transposed)
// block 2112: We_red for both layers -> wr[0..11], wr[16..27]
__global__ __launch_bounds__(256) void k_prepw(const float* __restrict__ h,
                                               const float* __restrict__ W1f,
                                               const float* __restrict__ W2f,
                                               const float* __restrict__ We1,
                                               const float* __restrict__ at1,
                                               const float* __restrict__ We2,
                                               const float* __restrict__ at2,
                                               ushort* __restrict__ zb,
                                               ushort* __restrict__ wt1,
                                               ushort* __restrict__ wt2,
                                               float* __restrict__ wr) {
    int t = threadIdx.x;
    if (blockIdx.x < 2048) {
        int i = blockIdx.x * 256 + t;
        float4 v = ((const float4*)h)[i];
        ushort4 o;
        o.x = f2bf(v.x); o.y = f2bf(v.y); o.z = f2bf(v.z); o.w = f2bf(v.w);
        ((ushort4*)zb)[i] = o;
    } else if (blockIdx.x < 2112) {
        int j = (blockIdx.x - 2048) * 256 + t;   // 0..16383
        int c = j >> 6, k = j & 63;
        wt1[j] = f2bf(W1f[k * HC + c]);
        wt2[j] = f2bf(W2f[k * HC + c]);
    } else {
        int wv = t >> 6, lane = t & 63;
#pragma unroll
        for (int it = 0; it < 6; ++it) {
            int comb = wv + it * 4;          // 0..23
            int layer = comb / 12;
            int dh = comb % 12;
            int d = dh >> 2, hh = dh & 3;
            const float* We = layer ? We2 : We1;
            const float* at = layer ? at2 : at1;
            float v = We[d * HC + hh * HIDDEN + lane] * at[hh * HIDDEN + lane];
            for (int o = 32; o > 0; o >>= 1) v += __shfl_down(v, o);
            if (lane == 0) wr[layer * 16 + d * HEADS + hh] = v;
        }
    }
}

// One-time per-edge prep (dst-sorted order): aes{1,2}[p][h] = edge_attr[e] @ wr,
// ssorted[p] = src. Random ea gather happens ONCE here instead of once per layer.
__global__ __launch_bounds__(256) void k_aes(
        const float* __restrict__ ea, const float* __restrict__ wr,
        const int2* __restrict__ es, float* __restrict__ aes1,
        float* __restrict__ aes2, int* __restrict__ ssorted, int E) {
    int p = blockIdx.x * blockDim.x + threadIdx.x;
    if (p >= E) return;
    int2 ep = es[p];
    float a0 = ea[ep.x * 3 + 0];
    float a1 = ea[ep.x * 3 + 1];
    float a2 = ea[ep.x * 3 + 2];
    ssorted[p] = ep.y;
    float o1[4], o2[4];
#pragma unroll
    for (int h = 0; h < 4; ++h) {
        o1[h] = a0 * wr[h] + a1 * wr[4 + h] + a2 * wr[8 + h];
        o2[h] = a0 * wr[16 + h] + a1 * wr[20 + h] + a2 * wr[24 + h];
    }
    *(float4*)&aes1[(size_t)p * 4] = make_float4(o1[0], o1[1], o1[2], o1[3]);
    *(float4*)&aes2[(size_t)p * 4] = make_float4(o2[0], o2[1], o2[2], o2[3]);
}

// ---------------- MFMA transform ----------------
// x = z @ W (64 -> 256) via mfma_f32_16x16x32_bf16, fused alpha_src/alpha_dst.
__global__ __launch_bounds__(256) void k_tmfma(const ushort* __restrict__ zb,
                                               const ushort* __restrict__ wt,
                                               const float* __restrict__ asw,
                                               const float* __restrict__ adw,
                                               ushort* __restrict__ xb,
                                               float* __restrict__ as_,
                                               float* __restrict__ ad_) {
    int wave = threadIdx.x >> 6, lane = threadIdx.x & 63;
    int q = lane & 15, quad = lane >> 4;
    int row0 = blockIdx.x * 64 + wave * 16;

    const ushort* zrow = zb + (size_t)(row0 + q) * 64 + quad * 8;
    short8 a0 = *(const short8*)(zrow);
    short8 a1 = *(const short8*)(zrow + 32);

#pragma unroll
    for (int h = 0; h < 4; ++h) {
        float vs[4] = {0.f, 0.f, 0.f, 0.f};
        float vd[4] = {0.f, 0.f, 0.f, 0.f};
#pragma unroll
        for (int nt = 0; nt < 4; ++nt) {
            int col0 = h * 64 + nt * 16;
            const ushort* wrow = wt + (size_t)(col0 + q) * 64 + quad * 8;
            short8 b0 = *(const short8*)(wrow);
            short8 b1 = *(const short8*)(wrow + 32);
            f32x4 acc = {0.f, 0.f, 0.f, 0.f};
            acc = __builtin_amdgcn_mfma_f32_16x16x32_bf16(a0, b0, acc, 0, 0, 0);
            acc = __builtin_amdgcn_mfma_f32_16x16x32_bf16(a1, b1, acc, 0, 0, 0);
            int c = col0 + q;
            float aw = asw[c], dw = adw[c];
#pragma unroll
            for (int r = 0; r < 4; ++r) {
                float v = acc[r];
                xb[(size_t)(row0 + quad * 4 + r) * HC + c] = f2bf(v);
                vs[r] += v * aw;
                vd[r] += v * dw;
            }
        }
#pragma unroll
        for (int o = 1; o < 16; o <<= 1) {
#pragma unroll
            for (int r = 0; r < 4; ++r) {
                vs[r] += __shfl_xor(vs[r], o);
                vd[r] += __shfl_xor(vd[r], o);
            }
        }
        if (q < 4) {
            int n = row0 + quad * 4 + q;
            as_[n * 4 + h] = vs[q];
            ad_[n * 4 + h] = vd[q];
        }
    }
}

// Single-pass flash-style aggregate: online softmax + gather in one loop.
// Wave per node (grid-stride, 2 nodes/wave). lane = h*16 + sub;
// sub = edge slot in chunk for stats; (e,g) = (sub&1, sub>>1) for gather.
__global__ __launch_bounds__(256) void k_aggregate(
        const ushort* __restrict__ xb, const float* __restrict__ aes,
        const int* __restrict__ ssorted, const int* __restrict__ offs,
        const float* __restrict__ as_, const float* __restrict__ ad_,
        const float* __restrict__ bias, const float* __restrict__ lng,
        const float* __restrict__ lnb, float* __restrict__ outf,
        ushort* __restrict__ outb, int N) {
    int lane = threadIdx.x & 63;
    int h = lane >> 4, sub = lane & 15;
    int e = sub & 1, g = sub >> 1;
    int wid = blockIdx.x * 4 + (threadIdx.x >> 6);
    int nwaves = gridDim.x * 4;

    float bs[8], gm[8], bt[8];
#pragma unroll
    for (int k = 0; k < 8; ++k) {
        bs[k] = bias[g * 8 + k];
        gm[k] = lng[g * 8 + k];
        bt[k] = lnb[g * 8 + k];
    }

    for (int n = wid; n < N; n += nwaves) {
        int beg = offs[n], deg = offs[n + 1] - beg;
        float ad4 = ad_[n * 4 + h];

        float m = -INFINITY, ssum = 0.f;
        float acc[8];
#pragma unroll
        for (int k = 0; k < 8; ++k) acc[k] = 0.f;

        for (int cs = 0; cs < deg; cs += 16) {
            int idx = cs + sub;
            bool valid = idx < deg;
            int s_sub = 0;
            float lg = -INFINITY;
            if (valid) {
                s_sub = ssorted[beg + idx];
                lg = as_[s_sub * 4 + h] + aes[(size_t)(beg + idx) * 4 + h] + ad4;
                lg = (lg >= 0.f) ? lg : 0.2f * lg;
            }
            // chunk max over the 16 lanes of this head group
            float cm = lg;
#pragma unroll
            for (int o = 1; o < 16; o <<= 1) cm = fmaxf(cm, __shfl_xor(cm, o));
            float mnew = fmaxf(m, cm);
            float scale = (m == -INFINITY) ? 0.f : __expf(m - mnew);
            float wgt = valid ? __expf(lg - mnew) : 0.f;
            float cw = wgt;
#pragma unroll
            for (int o = 1; o < 16; o <<= 1) cw += __shfl_xor(cw, o);
            ssum = ssum * scale + cw;
            m = mnew;
#pragma unroll
            for (int k = 0; k < 8; ++k) acc[k] *= scale;

            int jb = deg - cs; if (jb > 16) jb = 16;
            for (int j2 = 0; j2 < jb; j2 += 2) {
                int sl = h * 16 + j2 + e;
                float wj = __shfl(wgt, sl);
                int sj = __shfl(s_sub, sl);
                uint4 raw = *(const uint4*)&xb[(size_t)sj * HC + h * HIDDEN + g * 8];
                unsigned int u[4] = {raw.x, raw.y, raw.z, raw.w};
#pragma unroll
                for (int k = 0; k < 4; ++k) {
                    acc[2 * k + 0] += wj * __uint_as_float(u[k] << 16);
                    acc[2 * k + 1] += wj * __uint_as_float(u[k] & 0xffff0000u);
                }
            }
        }
        float winv = 1.f / (ssum + 1e-16f);
#pragma unroll
        for (int k = 0; k < 8; ++k) acc[k] *= winv;
        // reduce over edge slot (bit 0) and heads (bits 4,5)
#pragma unroll
        for (int k = 0; k < 8; ++k) {
            acc[k] += __shfl_xor(acc[k], 1);
            acc[k] += __shfl_xor(acc[k], 16);
            acc[k] += __shfl_xor(acc[k], 32);
        }

        // epilogue: head mean + bias + LayerNorm + SiLU (per-g lanes redundant)
        float u8[8], s1 = 0.f;
#pragma unroll
        for (int k = 0; k < 8; ++k) {
            u8[k] = acc[k] * 0.25f + bs[k];
            s1 += u8[k];
        }
#pragma unroll
        for (int o = 2; o < 16; o <<= 1) s1 += __shfl_xor(s1, o);
        float mu = s1 * (1.f / 64.f);
        float s2 = 0.f;
#pragma unroll
        for (int k = 0; k < 8; ++k) {
            float d = u8[k] - mu;
            s2 += d * d;
        }
#pragma unroll
        for (int o = 2; o < 16; o <<= 1) s2 += __shfl_xor(s2, o);
        float rstd = rsqrtf(s2 * (1.f / 64.f) + 1e-5f);
        float r[8];
#pragma unroll
        for (int k = 0; k < 8; ++k) {
            float y = (u8[k] - mu) * rstd * gm[k] + bt[k];
            r[k] = y / (1.f + __expf(-y));
        }
        if ((lane & 49) == 0) {   // h==0 && e==0: 8 lanes, one per g
            if (outb) {
                uint4 pk;
                pk.x = (unsigned)f2bf(r[0]) | ((unsigned)f2bf(r[1]) << 16);
                pk.y = (unsigned)f2bf(r[2]) | ((unsigned)f2bf(r[3]) << 16);
                pk.z = (unsigned)f2bf(r[4]) | ((unsigned)f2bf(r[5]) << 16);
                pk.w = (unsigned)f2bf(r[6]) | ((unsigned)f2bf(r[7]) << 16);
                *(uint4*)&outb[(size_t)n * HIDDEN + g * 8] = pk;
            } else {
                float4* o4 = (float4*)&outf[(size_t)n * HIDDEN + g * 8];
                o4[0] = make_float4(r[0], r[1], r[2], r[3]);
                o4[1] = make_float4(r[4], r[5], r[6], r[7]);
            }
        }
    }
}

// ---------------- launch ----------------

extern "C" void kernel_launch(void* const* d_in, const int* in_sizes, int n_in,
                              void* d_out, int out_size, void* d_ws, size_t ws_size,
                              hipStream_t stream) {
    const float* h   = (const float*)d_in[1];
    const int*   ei  = (const int*)d_in[2];
    const float* ea  = (const float*)d_in[3];
    const float* W1  = (const float*)d_in[4];
    const float* We1 = (const float*)d_in[5];
    const float* as1 = (const float*)d_in[6];
    const float* ad1 = (const float*)d_in[7];
    const float* ae1 = (const float*)d_in[8];
    const float* b1  = (const float*)d_in[9];
    const float* lg1 = (const float*)d_in[10];
    const float* lb1 = (const float*)d_in[11];
    const float* W2  = (const float*)d_in[12];
    const float* We2 = (const float*)d_in[13];
    const float* as2 = (const float*)d_in[14];
    const float* ad2 = (const float*)d_in[15];
    const float* ae2 = (const float*)d_in[16];
    const float* b2  = (const float*)d_in[17];
    const float* lg2 = (const float*)d_in[18];
    const float* lb2 = (const float*)d_in[19];

    const int N = in_sizes[1] / HIDDEN;   // 32768
    const int E = in_sizes[2] / 2;        // 262144
    const int* srcp = ei;
    const int* dstp = ei + E;

    // workspace layout (all regions fully written before read)
    char* w = (char*)d_ws;
    ushort* xb    = (ushort*)w; w += (size_t)N * HC * 2;       // 16.75 MB
    ushort* zb    = (ushort*)w; w += (size_t)N * HIDDEN * 2;   // 4 MB
    float* as_    = (float*)w;  w += (size_t)N * HEADS * 4;
    float* adv    = (float*)w;  w += (size_t)N * HEADS * 4;
    float* aes1   = (float*)w;  w += (size_t)E * 4 * 4;        // 4 MB
    float* aes2   = (float*)w;  w += (size_t)E * 4 * 4;        // 4 MB
    ushort* wt1   = (ushort*)w; w += 16384 * 2;
    ushort* wt2   = (ushort*)w; w += 16384 * 2;
    float* wr     = (float*)w;  w += 128;
    int* counts   = (int*)w;    w += (size_t)N * 4;
    int* cursor   = (int*)w;    w += (size_t)N * 4;
    int* offs     = (int*)w;    w += (size_t)(N + 1) * 4 + 124; // pad to 16B
    int* bsum     = (int*)w;    w += 128 * 4;
    int* bpre     = (int*)w;    w += 128 * 4;
    int2* es      = (int2*)w;   w += (size_t)E * 8;
    int* ssorted  = (int*)w;    w += (size_t)E * 4;

    // CSR by dst (shared across both layers)
    k_zero<<<(N + 255) / 256, 256, 0, stream>>>(counts, N);
    k_count<<<(E + 255) / 256, 256, 0, stream>>>(dstp, counts, E);
    k_bsum<<<N / 256, 256, 0, stream>>>(counts, bsum);
    k_bscan<<<1, 128, 0, stream>>>(bsum, bpre, offs, N);
    k_scanc<<<N / 256, 256, 0, stream>>>(counts, bpre, offs, cursor);
    k_fill<<<(E + 255) / 256, 256, 0, stream>>>(dstp, srcp, cursor, es, E);
    k_prepw<<<2113, 256, 0, stream>>>(h, W1, W2, We1, ae1, We2, ae2,
                                      zb, wt1, wt2, wr);
    k_aes<<<(E + 255) / 256, 256, 0, stream>>>(ea, wr, es, aes1, aes2, ssorted, E);

    // layer 1
    k_tmfma<<<N / 64, 256, 0, stream>>>(zb, wt1, as1, ad1, xb, as_, adv);
    k_aggregate<<<4096, 256, 0, stream>>>(xb, aes1, ssorted, offs, as_, adv,
                                          b1, lg1, lb1, nullptr, zb, N);
    // layer 2 (reads zb written by layer-1 aggregate)
    k_tmfma<<<N / 64, 256, 0, stream>>>(zb, wt2, as2, ad2, xb, as_, adv);
    k_aggregate<<<4096, 256, 0, stream>>>(xb, aes2, ssorted, offs, as_, adv,
                                          b2, lg2, lb2, (float*)d_out, nullptr, N);
}